// Round 1
// baseline (507.362 us; speedup 1.0000x reference)
//
#include <hip/hip_runtime.h>
#include <hip/hip_bf16.h>

// MultiHeadAttention: n=4096 tokens, e=128 head dim, H=8 heads, fp32 in/out.
// Pipeline: [K1] qkv fp32 GEMM + scatter (Q/K as bf16 hi+lo split, V d-major bf16)
//           [K2] flash attention, mfma_f32_16x16x32_bf16, split-bf16 QK^T (3 passes)
//           [K0] w_proj -> bf16 transposed   [K3] proj GEMM bf16 MFMA + K-split reduce
// Workspace: 5*8MB (Qhi,Qlo,Khi,Klo,Vt) + 8MB attout + 256KB wpT = ~48.5MB.

#define N_TOK 4096
#define DH 128
#define NH 8

typedef __attribute__((ext_vector_type(8))) short bf16x8;
typedef __attribute__((ext_vector_type(4))) float f32x4;

// ---------------- K1: QKV GEMM (fp32 vector) + scatter -------------------
// C[4096][3072] = x[4096][128] @ w_qkv[128][3072] + b_qkv
// col j -> h = j/384, d = (j%384)/3, s = j%3.  s=0:Q s=1:K s=2:V
__global__ __launch_bounds__(256) void qkv_gemm_scatter(
    const float* __restrict__ x, const float* __restrict__ w_qkv,
    const float* __restrict__ b_qkv,
    __hip_bfloat16* __restrict__ Qhi, __hip_bfloat16* __restrict__ Qlo,
    __hip_bfloat16* __restrict__ Khi, __hip_bfloat16* __restrict__ Klo,
    __hip_bfloat16* __restrict__ Vt)
{
  const int tid = threadIdx.x;
  const int mbase = blockIdx.y * 64;
  const int nbase = blockIdx.x * 64;
  const int tm = tid >> 4;   // 0..15 -> 4 rows each
  const int tn = tid & 15;   // 0..15 -> 4 cols each

  __shared__ float x_lds[64][68];   // stride 68 dwords (mod32=4 -> 2-way, free)
  __shared__ float w_lds[64][64];

  float acc[4][4] = {};

  for (int kc = 0; kc < 2; ++kc) {   // K = 2 x 64
    __syncthreads();
#pragma unroll
    for (int i = 0; i < 4; ++i) {    // x tile: 64 rows x 16 float4
      int c = tid + 256 * i;
      int row = c >> 4, off = c & 15;
      f32x4 v = *(const f32x4*)(x + (size_t)(mbase + row) * 128 + kc * 64 + off * 4);
      *(f32x4*)&x_lds[row][off * 4] = v;
    }
#pragma unroll
    for (int i = 0; i < 4; ++i) {    // w tile: 64 k x 16 float4
      int c = tid + 256 * i;
      int k = c >> 4, off = c & 15;
      f32x4 v = *(const f32x4*)(w_qkv + (size_t)(kc * 64 + k) * 3072 + nbase + off * 4);
      *(f32x4*)&w_lds[k][off * 4] = v;
    }
    __syncthreads();
#pragma unroll
    for (int k4 = 0; k4 < 16; ++k4) {
      f32x4 a[4], b[4];
#pragma unroll
      for (int i = 0; i < 4; ++i) a[i] = *(const f32x4*)&x_lds[tm * 4 + i][k4 * 4];
#pragma unroll
      for (int kk = 0; kk < 4; ++kk) b[kk] = *(const f32x4*)&w_lds[k4 * 4 + kk][tn * 4];
#pragma unroll
      for (int i = 0; i < 4; ++i)
#pragma unroll
        for (int j = 0; j < 4; ++j)
          acc[i][j] += a[i][0] * b[0][j] + a[i][1] * b[1][j]
                     + a[i][2] * b[2][j] + a[i][3] * b[3][j];
    }
  }

#pragma unroll
  for (int i = 0; i < 4; ++i) {
    int row = mbase + tm * 4 + i;
#pragma unroll
    for (int j = 0; j < 4; ++j) {
      int col = nbase + tn * 4 + j;
      float val = acc[i][j] + b_qkv[col];
      int hh = col / 384;
      int rem = col - hh * 384;
      int dd = rem / 3;
      int s = rem - dd * 3;
      if (s == 2) {
        Vt[(size_t)(hh * DH + dd) * N_TOK + row] = __float2bfloat16(val);
      } else {
        __hip_bfloat16 hi = __float2bfloat16(val);
        __hip_bfloat16 lo = __float2bfloat16(val - __bfloat162float(hi));
        size_t idx = (size_t)(hh * N_TOK + row) * DH + dd;
        if (s == 0) { Qhi[idx] = hi; Qlo[idx] = lo; }
        else        { Khi[idx] = hi; Klo[idx] = lo; }
      }
    }
  }
}

// ---------------- K2: flash attention ------------------------------------
// grid (64 q-tiles, 8 heads), 256 thr = 4 waves x 16 q-rows.
// KBLK=64 keys per iteration. S = Q K^T via 3-pass split bf16; online softmax;
// O += P V via per-wave P_lds (C-layout -> A-layout) and d-major V tile.
__global__ __launch_bounds__(256) void flash_attn(
    const __hip_bfloat16* __restrict__ Qhi, const __hip_bfloat16* __restrict__ Qlo,
    const __hip_bfloat16* __restrict__ Khi, const __hip_bfloat16* __restrict__ Klo,
    const __hip_bfloat16* __restrict__ Vt, __hip_bfloat16* __restrict__ attout)
{
  const int h = blockIdx.y;
  const int qb = blockIdx.x;
  const int tid = threadIdx.x;
  const int w = tid >> 6;
  const int lane = tid & 63;
  const int l16 = lane & 15;
  const int lhi = lane >> 4;

  // padded strides: 136 bf16 = 272B (68 dwords, mod32=4 -> 2-way);
  //                 72 bf16 = 144B (36 dwords, mod32=4 -> 2-way)
  __shared__ __hip_bfloat16 khi_lds[64][136];
  __shared__ __hip_bfloat16 klo_lds[64][136];
  __shared__ __hip_bfloat16 vt_lds[128][72];
  __shared__ __hip_bfloat16 p_lds[4][16][72];

  // Q fragments: lane holds Q[row=l16][k = kt*32 + lhi*8 + j]
  bf16x8 qhi[4], qlo[4];
  {
    const int qrow = qb * 64 + w * 16 + l16;
    const __hip_bfloat16* qph = Qhi + (size_t)(h * N_TOK + qrow) * DH + lhi * 8;
    const __hip_bfloat16* qpl = Qlo + (size_t)(h * N_TOK + qrow) * DH + lhi * 8;
#pragma unroll
    for (int kt = 0; kt < 4; ++kt) {
      qhi[kt] = *(const bf16x8*)(qph + kt * 32);
      qlo[kt] = *(const bf16x8*)(qpl + kt * 32);
    }
  }

  f32x4 o[8];
#pragma unroll
  for (int dt = 0; dt < 8; ++dt) o[dt] = (f32x4){0.f, 0.f, 0.f, 0.f};
  float m[4] = {-1e30f, -1e30f, -1e30f, -1e30f};
  float lsum[4] = {0.f, 0.f, 0.f, 0.f};

  char* khi_b = (char*)&khi_lds[0][0];
  char* klo_b = (char*)&klo_lds[0][0];
  char* vt_b  = (char*)&vt_lds[0][0];
  char* p_b   = (char*)&p_lds[w][0][0];

  for (int kb = 0; kb < N_TOK / 64; ++kb) {
    __syncthreads();
    // stage K hi/lo: 64 rows x 16 chunks(8 bf16)
#pragma unroll
    for (int i = 0; i < 4; ++i) {
      int c = tid + 256 * i;
      int row = c >> 4, off = c & 15;
      size_t g = (size_t)(h * N_TOK + kb * 64 + row) * DH + off * 8;
      *(bf16x8*)(khi_b + row * 272 + off * 16) = *(const bf16x8*)(Khi + g);
      *(bf16x8*)(klo_b + row * 272 + off * 16) = *(const bf16x8*)(Klo + g);
    }
    // stage V (d-major): 128 d-rows x 8 chunks(8 keys)
#pragma unroll
    for (int i = 0; i < 4; ++i) {
      int c = tid + 256 * i;
      int dd = c >> 3, off = c & 7;
      *(bf16x8*)(vt_b + dd * 144 + off * 16) =
          *(const bf16x8*)(Vt + (size_t)(h * DH + dd) * N_TOK + kb * 64 + off * 8);
    }
    __syncthreads();

    // S = Q K^T  (16 q-rows x 64 keys per wave)
    f32x4 s[4];
#pragma unroll
    for (int nt = 0; nt < 4; ++nt) {
      f32x4 acc = (f32x4){0.f, 0.f, 0.f, 0.f};
#pragma unroll
      for (int kt = 0; kt < 4; ++kt) {
        int key = nt * 16 + l16;
        int koff = kt * 32 + lhi * 8;
        bf16x8 bhi = *(const bf16x8*)(khi_b + key * 272 + koff * 2);
        bf16x8 blo = *(const bf16x8*)(klo_b + key * 272 + koff * 2);
        acc = __builtin_amdgcn_mfma_f32_16x16x32_bf16(qhi[kt], bhi, acc, 0, 0, 0);
        acc = __builtin_amdgcn_mfma_f32_16x16x32_bf16(qhi[kt], blo, acc, 0, 0, 0);
        acc = __builtin_amdgcn_mfma_f32_16x16x32_bf16(qlo[kt], bhi, acc, 0, 0, 0);
      }
      s[nt] = acc;
    }

    // online softmax: lane owns rows lhi*4+r at cols nt*16+l16
#pragma unroll
    for (int r = 0; r < 4; ++r) {
      float mx = fmaxf(fmaxf(s[0][r], s[1][r]), fmaxf(s[2][r], s[3][r]));
      mx = fmaxf(mx, __shfl_xor(mx, 1));
      mx = fmaxf(mx, __shfl_xor(mx, 2));
      mx = fmaxf(mx, __shfl_xor(mx, 4));
      mx = fmaxf(mx, __shfl_xor(mx, 8));
      float mnew = fmaxf(m[r], mx);
      float sc = __expf(m[r] - mnew);
      float psum = 0.f;
#pragma unroll
      for (int nt = 0; nt < 4; ++nt) {
        float p = __expf(s[nt][r] - mnew);
        s[nt][r] = p;
        psum += p;
      }
      psum += __shfl_xor(psum, 1);
      psum += __shfl_xor(psum, 2);
      psum += __shfl_xor(psum, 4);
      psum += __shfl_xor(psum, 8);
      lsum[r] = lsum[r] * sc + psum;
      m[r] = mnew;
#pragma unroll
      for (int dt = 0; dt < 8; ++dt) o[dt][r] *= sc;
#pragma unroll
      for (int nt = 0; nt < 4; ++nt)
        p_lds[w][lhi * 4 + r][nt * 16 + l16] = __float2bfloat16(s[nt][r]);
    }

    // O += P V : A = P[row=l16][k=ks*32+lhi*8+j], B = V[k=key][col=d] from vt_lds[d][key]
#pragma unroll
    for (int ks = 0; ks < 2; ++ks) {
      bf16x8 pa = *(const bf16x8*)(p_b + l16 * 144 + (ks * 32 + lhi * 8) * 2);
#pragma unroll
      for (int dt = 0; dt < 8; ++dt) {
        bf16x8 bv = *(const bf16x8*)(vt_b + (dt * 16 + l16) * 144 + (ks * 32 + lhi * 8) * 2);
        o[dt] = __builtin_amdgcn_mfma_f32_16x16x32_bf16(pa, bv, o[dt], 0, 0, 0);
      }
    }
  }

  // epilogue: att = softmax/sqrt(128) -> O / (lsum * sqrt(128))
  const float isc = 0.08838834764831845f;  // 1/sqrt(128)
#pragma unroll
  for (int r = 0; r < 4; ++r) {
    float rl = isc / lsum[r];
    int row = qb * 64 + w * 16 + lhi * 4 + r;
#pragma unroll
    for (int dt = 0; dt < 8; ++dt)
      attout[(size_t)row * (NH * DH) + h * DH + dt * 16 + l16] =
          __float2bfloat16(o[dt][r] * rl);
  }
}

// ---------------- K0: w_proj -> bf16 transposed [128 out][1024 in] -------
__global__ __launch_bounds__(256) void conv_wproj(
    const float* __restrict__ w_proj, __hip_bfloat16* __restrict__ wpT)
{
  int t = blockIdx.x * 256 + threadIdx.x;   // 131072 = 1024*128
  int k = t >> 7, col = t & 127;
  wpT[col * 1024 + k] = __float2bfloat16(w_proj[t]);
}

// ---------------- K3: proj GEMM ------------------------------------------
// out[4096][128] = attout[4096][1024](bf16) @ w_proj + b_proj.
// 256 blocks x 16 rows; 4 waves split K=1024; LDS reduce.
__global__ __launch_bounds__(256) void proj_gemm(
    const __hip_bfloat16* __restrict__ attout, const __hip_bfloat16* __restrict__ wpT,
    const float* __restrict__ b_proj, float* __restrict__ out)
{
  const int tid = threadIdx.x;
  const int w = tid >> 6;
  const int lane = tid & 63;
  const int l16 = lane & 15, lhi = lane >> 4;
  const int rb = blockIdx.x * 16;

  f32x4 o[8];
#pragma unroll
  for (int dt = 0; dt < 8; ++dt) o[dt] = (f32x4){0.f, 0.f, 0.f, 0.f};

#pragma unroll
  for (int kb = 0; kb < 8; ++kb) {
    int k0 = w * 256 + kb * 32 + lhi * 8;
    bf16x8 a = *(const bf16x8*)(attout + (size_t)(rb + l16) * 1024 + k0);
#pragma unroll
    for (int dt = 0; dt < 8; ++dt) {
      bf16x8 b = *(const bf16x8*)(wpT + (size_t)(dt * 16 + l16) * 1024 + k0);
      o[dt] = __builtin_amdgcn_mfma_f32_16x16x32_bf16(a, b, o[dt], 0, 0, 0);
    }
  }

  __shared__ float red[4][16][128];
#pragma unroll
  for (int dt = 0; dt < 8; ++dt)
#pragma unroll
    for (int r = 0; r < 4; ++r)
      red[w][lhi * 4 + r][dt * 16 + l16] = o[dt][r];
  __syncthreads();
#pragma unroll
  for (int i = 0; i < 8; ++i) {
    int idx = tid + 256 * i;
    int row = idx >> 7, col = idx & 127;
    float v = red[0][row][col] + red[1][row][col] + red[2][row][col]
            + red[3][row][col] + b_proj[col];
    out[(size_t)(rb + row) * 128 + col] = v;
  }
}

// ---------------- launch --------------------------------------------------
extern "C" void kernel_launch(void* const* d_in, const int* in_sizes, int n_in,
                              void* d_out, int out_size, void* d_ws, size_t ws_size,
                              hipStream_t stream) {
  const float* x      = (const float*)d_in[0];
  const float* w_qkv  = (const float*)d_in[1];
  const float* b_qkv  = (const float*)d_in[2];
  const float* w_proj = (const float*)d_in[3];
  const float* b_proj = (const float*)d_in[4];
  float* out = (float*)d_out;

  char* ws = (char*)d_ws;
  const size_t SZ = (size_t)NH * N_TOK * DH * sizeof(__hip_bfloat16);  // 8MB
  __hip_bfloat16* Qhi    = (__hip_bfloat16*)(ws + 0 * SZ);
  __hip_bfloat16* Qlo    = (__hip_bfloat16*)(ws + 1 * SZ);
  __hip_bfloat16* Khi    = (__hip_bfloat16*)(ws + 2 * SZ);
  __hip_bfloat16* Klo    = (__hip_bfloat16*)(ws + 3 * SZ);
  __hip_bfloat16* Vt     = (__hip_bfloat16*)(ws + 4 * SZ);
  __hip_bfloat16* attout = (__hip_bfloat16*)(ws + 5 * SZ);  // [4096][1024]
  __hip_bfloat16* wpT    = (__hip_bfloat16*)(ws + 6 * SZ);  // [128][1024]

  hipLaunchKernelGGL(conv_wproj, dim3(512), dim3(256), 0, stream, w_proj, wpT);
  hipLaunchKernelGGL(qkv_gemm_scatter, dim3(48, 64), dim3(256), 0, stream,
                     x, w_qkv, b_qkv, Qhi, Qlo, Khi, Klo, Vt);
  hipLaunchKernelGGL(flash_attn, dim3(64, 8), dim3(256), 0, stream,
                     Qhi, Qlo, Khi, Klo, Vt, attout);
  hipLaunchKernelGGL(proj_gemm, dim3(256), dim3(256), 0, stream,
                     attout, wpT, b_proj, out);
}

// Round 3
// 258.142 us; speedup vs baseline: 1.9654x; 1.9654x over previous
//
#include <hip/hip_runtime.h>
#include <hip/hip_fp16.h>

// MultiHeadAttention: n=4096, e=128, H=8, fp32 in/out.
// [K1] qkv fp32 GEMM -> Qh/Kh (f16 n-major), Vt (f16 d-major)
// [K2] flash attn: swapped QK^T (mfma(K,Q)) -> lane-local softmax -> in-lane
//      P repack (permuted key tiling) -> PV. fp16 single-pass, 16x16x32 mfma.
//      4 waves x 32 qrows = 128 qrows/block; KBLK=64; dbuf LDS + 2-phase.
// [K0] w_proj -> f16^T   [K3] proj GEMM f16 MFMA + K-split reduce

#define N_TOK 4096
#define DH 128
#define NH 8

typedef _Float16 f16;
typedef __attribute__((ext_vector_type(8))) _Float16 f16x8;
typedef __attribute__((ext_vector_type(2))) __fp16 hf2;   // cvt_pkrtz result type
typedef __attribute__((ext_vector_type(4))) float f32x4;

#define GLD16(gsrc, ldst) __builtin_amdgcn_global_load_lds( \
    (const __attribute__((address_space(1))) void*)(gsrc), \
    (__attribute__((address_space(3))) void*)(ldst), 16, 0, 0)

// ---------------- K1: QKV GEMM (fp32 vector) + scatter -------------------
// col j -> h = j/384, d = (j%384)/3, s = j%3.  s=0:Q s=1:K s=2:V
__global__ __launch_bounds__(256) void qkv_gemm_scatter(
    const float* __restrict__ x, const float* __restrict__ w_qkv,
    const float* __restrict__ b_qkv,
    f16* __restrict__ Qh, f16* __restrict__ Kh, f16* __restrict__ Vt)
{
  const int tid = threadIdx.x;
  const int mbase = blockIdx.y * 64;
  const int nbase = blockIdx.x * 64;
  const int tm = tid >> 4;
  const int tn = tid & 15;

  __shared__ float x_lds[64][68];
  __shared__ float w_lds[64][64];

  float acc[4][4] = {};

  for (int kc = 0; kc < 2; ++kc) {
    __syncthreads();
#pragma unroll
    for (int i = 0; i < 4; ++i) {
      int c = tid + 256 * i;
      int row = c >> 4, off = c & 15;
      f32x4 v = *(const f32x4*)(x + (size_t)(mbase + row) * 128 + kc * 64 + off * 4);
      *(f32x4*)&x_lds[row][off * 4] = v;
    }
#pragma unroll
    for (int i = 0; i < 4; ++i) {
      int c = tid + 256 * i;
      int k = c >> 4, off = c & 15;
      f32x4 v = *(const f32x4*)(w_qkv + (size_t)(kc * 64 + k) * 3072 + nbase + off * 4);
      *(f32x4*)&w_lds[k][off * 4] = v;
    }
    __syncthreads();
#pragma unroll
    for (int k4 = 0; k4 < 16; ++k4) {
      f32x4 a[4], b[4];
#pragma unroll
      for (int i = 0; i < 4; ++i) a[i] = *(const f32x4*)&x_lds[tm * 4 + i][k4 * 4];
#pragma unroll
      for (int kk = 0; kk < 4; ++kk) b[kk] = *(const f32x4*)&w_lds[k4 * 4 + kk][tn * 4];
#pragma unroll
      for (int i = 0; i < 4; ++i)
#pragma unroll
        for (int j = 0; j < 4; ++j)
          acc[i][j] += a[i][0] * b[0][j] + a[i][1] * b[1][j]
                     + a[i][2] * b[2][j] + a[i][3] * b[3][j];
    }
  }

#pragma unroll
  for (int i = 0; i < 4; ++i) {
    int row = mbase + tm * 4 + i;
#pragma unroll
    for (int j = 0; j < 4; ++j) {
      int col = nbase + tn * 4 + j;
      float val = acc[i][j] + b_qkv[col];
      int hh = col / 384;
      int rem = col - hh * 384;
      int dd = rem / 3;
      int s = rem - dd * 3;
      f16 hv = (f16)val;
      if (s == 2)      Vt[(size_t)(hh * DH + dd) * N_TOK + row] = hv;
      else if (s == 0) Qh[(size_t)(hh * N_TOK + row) * DH + dd] = hv;
      else             Kh[(size_t)(hh * N_TOK + row) * DH + dd] = hv;
    }
  }
}

// ---------------- K2: flash attention ------------------------------------
__global__ __launch_bounds__(256) void flash_attn(
    const f16* __restrict__ Qh, const f16* __restrict__ Kh,
    const f16* __restrict__ Vt, f16* __restrict__ attout)
{
  const int bid = blockIdx.x;
  const int h = bid & 7, qb = bid >> 3;   // h = XCD selector (round-robin dispatch)
  const int tid = threadIdx.x;
  const int w = tid >> 6, lane = tid & 63;
  const int l16 = lane & 15, lhi = lane >> 4;

  // smem: kbuf[2] @ 0/16K (each [64 tok][128 d] f16, XOR-swz), vbuf[2] @ 32K/48K
  // (each [128 d][64 tok] f16, XOR-swz). Epilogue reuses [128][136] f16 tile.
  __shared__ __align__(16) char smem[65536];

  // Q fragments (B-operand): lane holds Q[qrow=l16(+16m)][kt*32 + lhi*8 + j]
  f16x8 qf[2][4];
#pragma unroll
  for (int m = 0; m < 2; ++m)
#pragma unroll
    for (int kt = 0; kt < 4; ++kt)
      qf[m][kt] = *(const f16x8*)(Qh +
          (size_t)(h * N_TOK + qb * 128 + w * 32 + m * 16 + l16) * DH + kt * 32 + lhi * 8);

  // Lane-constant LDS byte offsets.
  // K A-row permutation: tile nt, frag-row i=l16 -> K row
  //   pi = 32*(nt>>1) + 8*(i>>2) + 4*(nt&1) + (i&3)
  // => lane's S^T keys = {32b1 + 8lhi + 4b0 + r} == PV B-frag key set (in-lane repack).
  int koff[4][4], voff[2][8];
#pragma unroll
  for (int nt = 0; nt < 4; ++nt) {
    int row = 32 * (nt >> 1) + 8 * (l16 >> 2) + 4 * (nt & 1) + (l16 & 3);
    int fk = (row & 3) | ((row & 8) >> 1);          // 3-bit swizzle key
#pragma unroll
    for (int kt = 0; kt < 4; ++kt)
      koff[nt][kt] = row * 256 + ((kt * 4 + lhi) ^ fk) * 16;
  }
#pragma unroll
  for (int ks = 0; ks < 2; ++ks)
#pragma unroll
    for (int dt = 0; dt < 8; ++dt) {
      int rowv = dt * 16 + l16;
      voff[ks][dt] = rowv * 128 + (((ks * 4 + lhi) ^ (rowv & 7))) * 16;
    }

  f32x4 o[2][8];
#pragma unroll
  for (int m = 0; m < 2; ++m)
#pragma unroll
    for (int dt = 0; dt < 8; ++dt) o[m][dt] = (f32x4){0.f, 0.f, 0.f, 0.f};
  float mrun[2] = {-3e38f, -3e38f}, lrun[2] = {0.f, 0.f};

  const f16* Kgh = Kh + (size_t)h * N_TOK * DH;
  const f16* Vgh = Vt + (size_t)h * DH * N_TOK;

  // stage: wave w loads 4 KB of K + 4 KB of V; LDS dest linear, swizzle applied
  // on the per-lane GLOBAL source (rule 21).
  auto stage = [&](int buf, int kb) {
    char* kd = smem + buf * 16384;
    char* vd = smem + 32768 + buf * 16384;
#pragma unroll
    for (int c4 = 0; c4 < 4; ++c4) {
      int c = w * 4 + c4;
      {
        int row = c * 4 + (lane >> 4);
        int fk = (row & 3) | ((row & 8) >> 1);
        const f16* src = Kgh + (size_t)(kb * 64 + row) * DH + ((lane & 15) ^ fk) * 8;
        GLD16(src, kd + c * 1024);
      }
      {
        int row = c * 8 + (lane >> 3);
        const f16* src = Vgh + (size_t)row * N_TOK + kb * 64 + ((lane & 7) ^ (row & 7)) * 8;
        GLD16(src, vd + c * 1024);
      }
    }
  };

  stage(0, 0);
  __syncthreads();
  int buf = 0;
  for (int kb = 0; kb < N_TOK / 64; ++kb) {
    if (kb < N_TOK / 64 - 1) stage(buf ^ 1, kb + 1);   // prefetch next tile
    const char* kd = smem + buf * 16384;
    const char* vd = smem + 32768 + buf * 16384;

    // S^T = mfma(K, Q): D[key][qrow], qrow = l16, key = permuted per koff
    f32x4 sv[2][4];
#pragma unroll
    for (int nt = 0; nt < 4; ++nt) {
      f32x4 a0 = {0.f, 0.f, 0.f, 0.f}, a1 = {0.f, 0.f, 0.f, 0.f};
#pragma unroll
      for (int kt = 0; kt < 4; ++kt) {
        f16x8 kf = *(const f16x8*)(kd + koff[nt][kt]);
        a0 = __builtin_amdgcn_mfma_f32_16x16x32_f16(kf, qf[0][kt], a0, 0, 0, 0);
        a1 = __builtin_amdgcn_mfma_f32_16x16x32_f16(kf, qf[1][kt], a1, 0, 0, 0);
      }
      sv[0][nt] = a0; sv[1][nt] = a1;
    }

    // online softmax, fully lane-local rows + 2 shfls; in-lane P repack
    f16x8 pf[2][2];
#pragma unroll
    for (int m = 0; m < 2; ++m) {
      f32x4 mv;
#pragma unroll
      for (int r = 0; r < 4; ++r)
        mv[r] = fmaxf(fmaxf(sv[m][0][r], sv[m][1][r]), fmaxf(sv[m][2][r], sv[m][3][r]));
      float pmax = fmaxf(fmaxf(mv[0], mv[1]), fmaxf(mv[2], mv[3]));
      pmax = fmaxf(pmax, __shfl_xor(pmax, 16));
      pmax = fmaxf(pmax, __shfl_xor(pmax, 32));
      float mnew = fmaxf(mrun[m], pmax);
      float sc = __expf(mrun[m] - mnew);
      mrun[m] = mnew;
      f32x4 ps = {0.f, 0.f, 0.f, 0.f};
#pragma unroll
      for (int nt = 0; nt < 4; ++nt)
#pragma unroll
        for (int r = 0; r < 4; ++r) {
          float p = __expf(sv[m][nt][r] - mnew);
          sv[m][nt][r] = p;
          ps[r] += p;
        }
      float psum = (ps[0] + ps[1]) + (ps[2] + ps[3]);
      psum += __shfl_xor(psum, 16);
      psum += __shfl_xor(psum, 32);
      lrun[m] = lrun[m] * sc + psum;
#pragma unroll
      for (int dt = 0; dt < 8; ++dt) o[m][dt] *= sc;
      // B-frag(ks) elements = [t(2ks)r0..r3, t(2ks+1)r0..r3] — all in-lane
#pragma unroll
      for (int ks = 0; ks < 2; ++ks) {
        union { f16x8 v; hf2 hh[4]; } u;
        u.hh[0] = __builtin_amdgcn_cvt_pkrtz(sv[m][2 * ks][0], sv[m][2 * ks][1]);
        u.hh[1] = __builtin_amdgcn_cvt_pkrtz(sv[m][2 * ks][2], sv[m][2 * ks][3]);
        u.hh[2] = __builtin_amdgcn_cvt_pkrtz(sv[m][2 * ks + 1][0], sv[m][2 * ks + 1][1]);
        u.hh[3] = __builtin_amdgcn_cvt_pkrtz(sv[m][2 * ks + 1][2], sv[m][2 * ks + 1][3]);
        pf[m][ks] = u.v;
      }
    }

    // O^T += mfma(V^T, P^T): D[d][qrow]; V frag shared across both m halves
#pragma unroll
    for (int ks = 0; ks < 2; ++ks)
#pragma unroll
      for (int dt = 0; dt < 8; ++dt) {
        f16x8 vf = *(const f16x8*)(vd + voff[ks][dt]);
        o[0][dt] = __builtin_amdgcn_mfma_f32_16x16x32_f16(vf, pf[0][ks], o[0][dt], 0, 0, 0);
        o[1][dt] = __builtin_amdgcn_mfma_f32_16x16x32_f16(vf, pf[1][ks], o[1][dt], 0, 0, 0);
      }

    __syncthreads();
    buf ^= 1;
  }

  // epilogue: O^T -> LDS [qrow][d] (f16) -> coalesced global store
  const float isc = 0.08838834764831845f;  // 1/sqrt(128), post-softmax scale
#pragma unroll
  for (int m = 0; m < 2; ++m) {
    float rl = isc / lrun[m];
    int qrow = w * 32 + m * 16 + l16;
#pragma unroll
    for (int dt = 0; dt < 8; ++dt) {
      hf2 p0 = __builtin_amdgcn_cvt_pkrtz(o[m][dt][0] * rl, o[m][dt][1] * rl);
      hf2 p1 = __builtin_amdgcn_cvt_pkrtz(o[m][dt][2] * rl, o[m][dt][3] * rl);
      *(hf2*)(smem + qrow * 272 + dt * 32 + lhi * 8 + 0) = p0;
      *(hf2*)(smem + qrow * 272 + dt * 32 + lhi * 8 + 4) = p1;
    }
  }
  __syncthreads();
  {
    int r2 = tid >> 1, half = tid & 1;
#pragma unroll
    for (int i = 0; i < 8; ++i) {
      f16x8 v = *(const f16x8*)(smem + r2 * 272 + half * 128 + i * 16);
      *(f16x8*)(attout + (size_t)(qb * 128 + r2) * (NH * DH) + h * DH + half * 64 + i * 8) = v;
    }
  }
}

// ---------------- K0: w_proj -> f16 transposed [128 out][1024 in] --------
__global__ __launch_bounds__(256) void conv_wproj(
    const float* __restrict__ w_proj, f16* __restrict__ wpT)
{
  int t = blockIdx.x * 256 + threadIdx.x;   // 131072 = 1024*128
  int k = t >> 7, col = t & 127;
  wpT[col * 1024 + k] = (f16)w_proj[t];
}

// ---------------- K3: proj GEMM ------------------------------------------
__global__ __launch_bounds__(256) void proj_gemm(
    const f16* __restrict__ attout, const f16* __restrict__ wpT,
    const float* __restrict__ b_proj, float* __restrict__ out)
{
  const int tid = threadIdx.x;
  const int w = tid >> 6;
  const int lane = tid & 63;
  const int l16 = lane & 15, lhi = lane >> 4;
  const int rb = blockIdx.x * 16;

  f32x4 o[8];
#pragma unroll
  for (int dt = 0; dt < 8; ++dt) o[dt] = (f32x4){0.f, 0.f, 0.f, 0.f};

#pragma unroll
  for (int kb = 0; kb < 8; ++kb) {
    int k0 = w * 256 + kb * 32 + lhi * 8;
    f16x8 a = *(const f16x8*)(attout + (size_t)(rb + l16) * 1024 + k0);
#pragma unroll
    for (int dt = 0; dt < 8; ++dt) {
      f16x8 b = *(const f16x8*)(wpT + (size_t)(dt * 16 + l16) * 1024 + k0);
      o[dt] = __builtin_amdgcn_mfma_f32_16x16x32_f16(a, b, o[dt], 0, 0, 0);
    }
  }

  __shared__ float red[4][16][128];
#pragma unroll
  for (int dt = 0; dt < 8; ++dt)
#pragma unroll
    for (int r = 0; r < 4; ++r)
      red[w][lhi * 4 + r][dt * 16 + l16] = o[dt][r];
  __syncthreads();
#pragma unroll
  for (int i = 0; i < 8; ++i) {
    int idx = tid + 256 * i;
    int row = idx >> 7, col = idx & 127;
    float v = red[0][row][col] + red[1][row][col] + red[2][row][col]
            + red[3][row][col] + b_proj[col];
    out[(size_t)(rb + row) * 128 + col] = v;
  }
}

// ---------------- launch --------------------------------------------------
extern "C" void kernel_launch(void* const* d_in, const int* in_sizes, int n_in,
                              void* d_out, int out_size, void* d_ws, size_t ws_size,
                              hipStream_t stream) {
  const float* x      = (const float*)d_in[0];
  const float* w_qkv  = (const float*)d_in[1];
  const float* b_qkv  = (const float*)d_in[2];
  const float* w_proj = (const float*)d_in[3];
  const float* b_proj = (const float*)d_in[4];
  float* out = (float*)d_out;

  char* ws = (char*)d_ws;
  const size_t SZ = (size_t)NH * N_TOK * DH * sizeof(f16);  // 8MB
  f16* Qh     = (f16*)(ws + 0 * SZ);
  f16* Kh     = (f16*)(ws + 1 * SZ);
  f16* Vt     = (f16*)(ws + 2 * SZ);   // [h*128 + d][n]
  f16* attout = (f16*)(ws + 3 * SZ);   // [4096][1024]
  f16* wpT    = (f16*)(ws + 4 * SZ);   // [128][1024]

  hipLaunchKernelGGL(conv_wproj, dim3(512), dim3(256), 0, stream, w_proj, wpT);
  hipLaunchKernelGGL(qkv_gemm_scatter, dim3(48, 64), dim3(256), 0, stream,
                     x, w_qkv, b_qkv, Qh, Kh, Vt);
  hipLaunchKernelGGL(flash_attn, dim3(256), dim3(256), 0, stream,
                     Qh, Kh, Vt, attout);
  hipLaunchKernelGGL(proj_gemm, dim3(256), dim3(256), 0, stream,
                     attout, wpT, b_proj, out);
}

// Round 4
// 181.663 us; speedup vs baseline: 2.7929x; 1.4210x over previous
//
#include <hip/hip_runtime.h>
#include <hip/hip_fp16.h>

// MultiHeadAttention: n=4096, e=128, H=8, fp32 in/out.
// [conv_wproj]  w_proj -> f16^T [128 out][1024 in]
// [conv_wqkv]   w_qkv -> f16 permuted-transposed wqkvT[col'][k], col'=s*1024+h*128+d
// [qkv_gemm2]   f16 MFMA GEMM; V stored d-major, Q/K n-major via LDS transpose
// [flash_attn]  split-K x2 (grid 512 = 2 blocks/CU): swapped QK^T, lane-local
//               softmax, in-lane P repack, PV; writes unnormalized O^T f16 + (m,l)
// [proj_combine] fused split-K combine + proj GEMM
// Workspace ~41.5 MiB: Qh 8 | Kh 8 | Vt 8 | opart 16 | ml 0.5 | wpT 0.25 | wqkvT 0.75 | bperm

#define N_TOK 4096
#define DH 128
#define NH 8

typedef _Float16 f16;
typedef __attribute__((ext_vector_type(8))) _Float16 f16x8;
typedef __attribute__((ext_vector_type(2))) __fp16 hf2;
typedef __attribute__((ext_vector_type(4))) float f32x4;

#define GLD16(gsrc, ldst) __builtin_amdgcn_global_load_lds( \
    (const __attribute__((address_space(1))) void*)(gsrc), \
    (__attribute__((address_space(3))) void*)(ldst), 16, 0, 0)

// ---------------- conv: w_proj -> f16 transposed [128 out][1024 in] ------
__global__ __launch_bounds__(256) void conv_wproj(
    const float* __restrict__ w_proj, f16* __restrict__ wpT)
{
  int t = blockIdx.x * 256 + threadIdx.x;   // 131072
  int k = t >> 7, col = t & 127;
  wpT[col * 1024 + k] = (f16)w_proj[t];
}

// ---------------- conv: w_qkv -> permuted-transposed f16 -----------------
// col' = s*1024 + h*128 + d  <->  col = h*384 + d*3 + s
__global__ __launch_bounds__(256) void conv_wqkv(
    const float* __restrict__ w_qkv, const float* __restrict__ b_qkv,
    f16* __restrict__ wqkvT, float* __restrict__ bperm)
{
  int t = blockIdx.x * 256 + threadIdx.x;   // 393216 = 3072*128
  int colp = t >> 7, k = t & 127;
  int s = colp >> 10, rem = colp & 1023, hh = rem >> 7, d = rem & 127;
  int col = hh * 384 + d * 3 + s;
  wqkvT[t] = (f16)w_qkv[k * 3072 + col];
  if (k == 0) bperm[colp] = b_qkv[col];
}

// ---------------- qkv GEMM v2: f16 MFMA --------------------------------
// grid (24 col-blocks, 32 row-blocks). Each col-block = one (s, h), d in [0,128).
// out^T = mfma(A=W[col'][k], B=X[n][k]): D row = col', col = n.
__global__ __launch_bounds__(256) void qkv_gemm2(
    const float* __restrict__ x, const f16* __restrict__ wqkvT,
    const float* __restrict__ bperm,
    f16* __restrict__ Qh, f16* __restrict__ Kh, f16* __restrict__ Vt)
{
  const int cb = blockIdx.x;               // 0..23: s = cb>>3, h = cb&7
  const int rb = blockIdx.y;               // 0..31: rows rb*128
  const int tid = threadIdx.x;
  const int w = tid >> 6, lane = tid & 63;
  const int l16 = lane & 15, lhi = lane >> 4;
  const int s = cb >> 3, h = cb & 7;

  // X fragments (B-op): n = rb*128 + w*32 + m*16 + l16, k-chunk kt
  f16x8 xf[2][4];
#pragma unroll
  for (int m = 0; m < 2; ++m)
#pragma unroll
    for (int kt = 0; kt < 4; ++kt) {
      const float* xp = x + (size_t)(rb * 128 + w * 32 + m * 16 + l16) * 128 + kt * 32 + lhi * 8;
      f32x4 x0 = *(const f32x4*)xp, x1 = *(const f32x4*)(xp + 4);
      f16x8 v;
#pragma unroll
      for (int j = 0; j < 4; ++j) { v[j] = (f16)x0[j]; v[4 + j] = (f16)x1[j]; }
      xf[m][kt] = v;
    }

  f32x4 acc[8][2];
#pragma unroll
  for (int nt = 0; nt < 8; ++nt)
#pragma unroll
    for (int m = 0; m < 2; ++m) acc[nt][m] = (f32x4){0.f, 0.f, 0.f, 0.f};

#pragma unroll
  for (int nt = 0; nt < 8; ++nt)
#pragma unroll
    for (int kt = 0; kt < 4; ++kt) {
      f16x8 wf = *(const f16x8*)(wqkvT + (size_t)(cb * 128 + nt * 16 + l16) * 128 + kt * 32 + lhi * 8);
      acc[nt][0] = __builtin_amdgcn_mfma_f32_16x16x32_f16(wf, xf[0][kt], acc[nt][0], 0, 0, 0);
      acc[nt][1] = __builtin_amdgcn_mfma_f32_16x16x32_f16(wf, xf[1][kt], acc[nt][1], 0, 0, 0);
    }

#pragma unroll
  for (int nt = 0; nt < 8; ++nt) {
    f32x4 bb = *(const f32x4*)(bperm + cb * 128 + nt * 16 + 4 * lhi);
#pragma unroll
    for (int m = 0; m < 2; ++m) acc[nt][m] += bb;
  }

  if (s == 2) {            // V: direct d-major store [h*128+d][n]
#pragma unroll
    for (int nt = 0; nt < 8; ++nt)
#pragma unroll
      for (int m = 0; m < 2; ++m)
#pragma unroll
        for (int r = 0; r < 4; ++r)
          Vt[(size_t)(h * 128 + nt * 16 + 4 * lhi + r) * N_TOK + rb * 128 + w * 32 + m * 16 + l16] =
              (f16)acc[nt][m][r];
  } else {                 // Q/K: LDS transpose -> n-major [n][d]
    __shared__ f16 tr[128][136];
#pragma unroll
    for (int nt = 0; nt < 8; ++nt)
#pragma unroll
      for (int m = 0; m < 2; ++m)
#pragma unroll
        for (int r = 0; r < 4; ++r)
          tr[w * 32 + m * 16 + l16][nt * 16 + 4 * lhi + r] = (f16)acc[nt][m][r];
    __syncthreads();
    f16* dst = (s == 0 ? Qh : Kh) + (size_t)(h * N_TOK + rb * 128) * 128;
    int r = tid >> 1, dh = (tid & 1) * 64;
#pragma unroll
    for (int i = 0; i < 8; ++i)
      *(f16x8*)(dst + r * 128 + dh + i * 8) = *(const f16x8*)(&tr[r][dh + i * 8]);
  }
}

// ---------------- flash attention, split-K x2 ---------------------------
// grid 512: h = bid&7 (XCD pin), sp = (bid>>3)&1, qb = bid>>4.
// Writes unnormalized O^T (f16, [d][n]) + per-row (m, l) stats.
__global__ __launch_bounds__(256) void flash_attn(
    const f16* __restrict__ Qh, const f16* __restrict__ Kh,
    const f16* __restrict__ Vt, f16* __restrict__ opart, float* __restrict__ mlpart)
{
  const int bid = blockIdx.x;
  const int h = bid & 7, sp = (bid >> 3) & 1, qb = bid >> 4;
  const int tid = threadIdx.x;
  const int w = tid >> 6, lane = tid & 63;
  const int l16 = lane & 15, lhi = lane >> 4;

  __shared__ __align__(16) char smem[65536];   // kbuf[2] @0/16K, vbuf[2] @32K/48K

  f16x8 qf[2][4];
#pragma unroll
  for (int m = 0; m < 2; ++m)
#pragma unroll
    for (int kt = 0; kt < 4; ++kt)
      qf[m][kt] = *(const f16x8*)(Qh +
          (size_t)(h * N_TOK + qb * 128 + w * 32 + m * 16 + l16) * DH + kt * 32 + lhi * 8);

  // K A-row permutation pi = 32*(nt>>1) + 8*(i>>2) + 4*(nt&1) + (i&3); XOR swizzle
  int koff[4][4], voff[2][8];
#pragma unroll
  for (int nt = 0; nt < 4; ++nt) {
    int row = 32 * (nt >> 1) + 8 * (l16 >> 2) + 4 * (nt & 1) + (l16 & 3);
    int fk = (row & 3) | ((row & 8) >> 1);
#pragma unroll
    for (int kt = 0; kt < 4; ++kt)
      koff[nt][kt] = row * 256 + ((kt * 4 + lhi) ^ fk) * 16;
  }
#pragma unroll
  for (int ks = 0; ks < 2; ++ks)
#pragma unroll
    for (int dt = 0; dt < 8; ++dt) {
      int rowv = dt * 16 + l16;
      voff[ks][dt] = rowv * 128 + (((ks * 4 + lhi) ^ (rowv & 7))) * 16;
    }

  f32x4 o[2][8];
#pragma unroll
  for (int m = 0; m < 2; ++m)
#pragma unroll
    for (int dt = 0; dt < 8; ++dt) o[m][dt] = (f32x4){0.f, 0.f, 0.f, 0.f};
  float mrun[2] = {-3e38f, -3e38f}, lrun[2] = {0.f, 0.f};

  const f16* Kgh = Kh + (size_t)h * N_TOK * DH;
  const f16* Vgh = Vt + (size_t)h * DH * N_TOK;

  auto stage = [&](int buf, int kb) {
    char* kd = smem + buf * 16384;
    char* vd = smem + 32768 + buf * 16384;
#pragma unroll
    for (int c4 = 0; c4 < 4; ++c4) {
      int c = w * 4 + c4;
      {
        int row = c * 4 + (lane >> 4);
        int fk = (row & 3) | ((row & 8) >> 1);
        const f16* src = Kgh + (size_t)(kb * 64 + row) * DH + ((lane & 15) ^ fk) * 8;
        GLD16(src, kd + c * 1024);
      }
      {
        int row = c * 8 + (lane >> 3);
        const f16* src = Vgh + (size_t)row * N_TOK + kb * 64 + ((lane & 7) ^ (row & 7)) * 8;
        GLD16(src, vd + c * 1024);
      }
    }
  };

  const int kb0 = sp * 32;
  stage(0, kb0);
  __syncthreads();
  int buf = 0;
  for (int kb = kb0; kb < kb0 + 32; ++kb) {
    if (kb < kb0 + 31) stage(buf ^ 1, kb + 1);
    const char* kd = smem + buf * 16384;
    const char* vd = smem + 32768 + buf * 16384;

    f32x4 sv[2][4];
#pragma unroll
    for (int nt = 0; nt < 4; ++nt) {
      f32x4 a0 = {0.f, 0.f, 0.f, 0.f}, a1 = {0.f, 0.f, 0.f, 0.f};
#pragma unroll
      for (int kt = 0; kt < 4; ++kt) {
        f16x8 kf = *(const f16x8*)(kd + koff[nt][kt]);
        a0 = __builtin_amdgcn_mfma_f32_16x16x32_f16(kf, qf[0][kt], a0, 0, 0, 0);
        a1 = __builtin_amdgcn_mfma_f32_16x16x32_f16(kf, qf[1][kt], a1, 0, 0, 0);
      }
      sv[0][nt] = a0; sv[1][nt] = a1;
    }

    f16x8 pf[2][2];
#pragma unroll
    for (int m = 0; m < 2; ++m) {
      f32x4 mv;
#pragma unroll
      for (int r = 0; r < 4; ++r)
        mv[r] = fmaxf(fmaxf(sv[m][0][r], sv[m][1][r]), fmaxf(sv[m][2][r], sv[m][3][r]));
      float pmax = fmaxf(fmaxf(mv[0], mv[1]), fmaxf(mv[2], mv[3]));
      pmax = fmaxf(pmax, __shfl_xor(pmax, 16));
      pmax = fmaxf(pmax, __shfl_xor(pmax, 32));
      float mnew = fmaxf(mrun[m], pmax);
      float sc = __expf(mrun[m] - mnew);
      mrun[m] = mnew;
      f32x4 ps = {0.f, 0.f, 0.f, 0.f};
#pragma unroll
      for (int nt = 0; nt < 4; ++nt)
#pragma unroll
        for (int r = 0; r < 4; ++r) {
          float p = __expf(sv[m][nt][r] - mnew);
          sv[m][nt][r] = p;
          ps[r] += p;
        }
      float psum = (ps[0] + ps[1]) + (ps[2] + ps[3]);
      psum += __shfl_xor(psum, 16);
      psum += __shfl_xor(psum, 32);
      lrun[m] = lrun[m] * sc + psum;
#pragma unroll
      for (int dt = 0; dt < 8; ++dt) o[m][dt] *= sc;
#pragma unroll
      for (int ks = 0; ks < 2; ++ks) {
        union { f16x8 v; hf2 hh[4]; } u;
        u.hh[0] = __builtin_amdgcn_cvt_pkrtz(sv[m][2 * ks][0], sv[m][2 * ks][1]);
        u.hh[1] = __builtin_amdgcn_cvt_pkrtz(sv[m][2 * ks][2], sv[m][2 * ks][3]);
        u.hh[2] = __builtin_amdgcn_cvt_pkrtz(sv[m][2 * ks + 1][0], sv[m][2 * ks + 1][1]);
        u.hh[3] = __builtin_amdgcn_cvt_pkrtz(sv[m][2 * ks + 1][2], sv[m][2 * ks + 1][3]);
        pf[m][ks] = u.v;
      }
    }

#pragma unroll
    for (int ks = 0; ks < 2; ++ks)
#pragma unroll
      for (int dt = 0; dt < 8; ++dt) {
        f16x8 vf = *(const f16x8*)(vd + voff[ks][dt]);
        o[0][dt] = __builtin_amdgcn_mfma_f32_16x16x32_f16(vf, pf[0][ks], o[0][dt], 0, 0, 0);
        o[1][dt] = __builtin_amdgcn_mfma_f32_16x16x32_f16(vf, pf[1][ks], o[1][dt], 0, 0, 0);
      }

    __syncthreads();
    buf ^= 1;
  }

  // epilogue: unnormalized O^T f16 [128 d][128 n] + (m,l) stats
  f16* ob = opart + ((size_t)((sp * 8 + h) * 32 + qb)) * 16384;
  float* mlb = mlpart + ((size_t)((sp * 8 + h) * 32 + qb)) * 256;
#pragma unroll
  for (int m = 0; m < 2; ++m) {
#pragma unroll
    for (int dt = 0; dt < 8; ++dt)
#pragma unroll
      for (int r = 0; r < 4; ++r)
        ob[(dt * 16 + 4 * lhi + r) * 128 + w * 32 + m * 16 + l16] = (f16)o[m][dt][r];
    if (lhi == 0) {
      mlb[w * 32 + m * 16 + l16] = mrun[m];
      mlb[128 + w * 32 + m * 16 + l16] = lrun[m];
    }
  }
}

// ---------------- proj GEMM with fused split-K combine -------------------
// 256 blocks x 16 rows. Combine O0/O1 -> LDS A[16][1024], then MFMA vs wpT.
__global__ __launch_bounds__(256) void proj_combine(
    const f16* __restrict__ opart, const float* __restrict__ mlpart,
    const f16* __restrict__ wpT, const float* __restrict__ b_proj,
    float* __restrict__ out)
{
  const int tid = threadIdx.x;
  const int w = tid >> 6;
  const int lane = tid & 63;
  const int l16 = lane & 15, lhi = lane >> 4;
  const int rb = blockIdx.x * 16;
  const int qb = rb >> 7;            // opart tile
  const int nl0 = rb & 127;          // n offset within tile

  __shared__ f16 A[16][1032];        // [n][k = h*128+d], +8 pad
  __shared__ float wl[8][16][3];     // per (h, n): w0, w1, rl
  __shared__ float red[4][16][128];

  const float isc = 0.08838834764831845f;  // 1/sqrt(128)
  if (tid < 128) {
    int hh = tid >> 4, n = tid & 15;
    const float* ml0 = mlpart + ((size_t)((0 + hh) * 32 + qb)) * 256 + nl0 + n;
    const float* ml1 = mlpart + ((size_t)((8 + hh) * 32 + qb)) * 256 + nl0 + n;
    float m0 = ml0[0], l0 = ml0[128], m1 = ml1[0], l1 = ml1[128];
    float mt = fmaxf(m0, m1);
    float w0 = __expf(m0 - mt), w1 = __expf(m1 - mt);
    wl[hh][n][0] = w0; wl[hh][n][1] = w1;
    wl[hh][n][2] = isc / (l0 * w0 + l1 * w1);
  }
  __syncthreads();

  {
    int d = tid >> 1, nn = (tid & 1) * 8;
#pragma unroll
    for (int hh = 0; hh < 8; ++hh) {
      const f16* O0 = opart + ((size_t)((0 + hh) * 32 + qb)) * 16384 + d * 128 + nl0 + nn;
      const f16* O1 = opart + ((size_t)((8 + hh) * 32 + qb)) * 16384 + d * 128 + nl0 + nn;
      f16x8 a0 = *(const f16x8*)O0, a1 = *(const f16x8*)O1;
#pragma unroll
      for (int j = 0; j < 8; ++j) {
        int n = nn + j;
        float v = ((float)a0[j] * wl[hh][n][0] + (float)a1[j] * wl[hh][n][1]) * wl[hh][n][2];
        A[n][hh * 128 + d] = (f16)v;
      }
    }
  }
  __syncthreads();

  f32x4 o[8];
#pragma unroll
  for (int dt = 0; dt < 8; ++dt) o[dt] = (f32x4){0.f, 0.f, 0.f, 0.f};

#pragma unroll
  for (int kb = 0; kb < 8; ++kb) {
    int k0 = w * 256 + kb * 32 + lhi * 8;
    f16x8 a = *(const f16x8*)(&A[l16][k0]);
#pragma unroll
    for (int dt = 0; dt < 8; ++dt) {
      f16x8 b = *(const f16x8*)(wpT + (size_t)(dt * 16 + l16) * 1024 + k0);
      o[dt] = __builtin_amdgcn_mfma_f32_16x16x32_f16(a, b, o[dt], 0, 0, 0);
    }
  }

#pragma unroll
  for (int dt = 0; dt < 8; ++dt)
#pragma unroll
    for (int r = 0; r < 4; ++r)
      red[w][lhi * 4 + r][dt * 16 + l16] = o[dt][r];
  __syncthreads();
#pragma unroll
  for (int i = 0; i < 8; ++i) {
    int idx = tid + 256 * i;
    int row = idx >> 7, col = idx & 127;
    float v = red[0][row][col] + red[1][row][col] + red[2][row][col]
            + red[3][row][col] + b_proj[col];
    out[(size_t)(rb + row) * 128 + col] = v;
  }
}

// ---------------- launch --------------------------------------------------
extern "C" void kernel_launch(void* const* d_in, const int* in_sizes, int n_in,
                              void* d_out, int out_size, void* d_ws, size_t ws_size,
                              hipStream_t stream) {
  const float* x      = (const float*)d_in[0];
  const float* w_qkv  = (const float*)d_in[1];
  const float* b_qkv  = (const float*)d_in[2];
  const float* w_proj = (const float*)d_in[3];
  const float* b_proj = (const float*)d_in[4];
  float* out = (float*)d_out;

  char* ws = (char*)d_ws;
  const size_t MB = 1024 * 1024;
  f16*   Qh     = (f16*)(ws);                    // 8 MiB  [h][n][d]
  f16*   Kh     = (f16*)(ws + 8 * MB);           // 8 MiB  [h][n][d]
  f16*   Vt     = (f16*)(ws + 16 * MB);          // 8 MiB  [h][d][n]
  f16*   opart  = (f16*)(ws + 24 * MB);          // 16 MiB [sp][h][qb][d 128][n 128]
  float* mlpart = (float*)(ws + 40 * MB);        // 0.5 MiB
  f16*   wpT    = (f16*)(ws + 40 * MB + 512 * 1024);          // 0.25 MiB
  f16*   wqkvT  = (f16*)(ws + 40 * MB + 768 * 1024);          // 0.75 MiB
  float* bperm  = (float*)(ws + 41 * MB + 512 * 1024);        // 12 KiB

  hipLaunchKernelGGL(conv_wproj, dim3(512), dim3(256), 0, stream, w_proj, wpT);
  hipLaunchKernelGGL(conv_wqkv, dim3(1536), dim3(256), 0, stream, w_qkv, b_qkv, wqkvT, bperm);
  hipLaunchKernelGGL(qkv_gemm2, dim3(24, 32), dim3(256), 0, stream,
                     x, wqkvT, bperm, Qh, Kh, Vt);
  hipLaunchKernelGGL(flash_attn, dim3(512), dim3(256), 0, stream,
                     Qh, Kh, Vt, opart, mlpart);
  hipLaunchKernelGGL(proj_combine, dim3(256), dim3(256), 0, stream,
                     opart, mlpart, wpT, b_proj, out);
}

// Round 5
// 140.315 us; speedup vs baseline: 3.6159x; 1.2947x over previous
//
#include <hip/hip_runtime.h>
#include <hip/hip_fp16.h>

// MultiHeadAttention: n=4096, e=128, H=8, fp32 in/out.
// [conv_wproj]  w_proj -> f16^T [128 out][1024 in]
// [conv_wqkv]   w_qkv -> f16 permuted-transposed wqkvT[col'][k], col'=s*1024+h*128+d
// [qkv_gemm2]   f16 MFMA GEMM; V stored d-major, Q/K n-major via LDS transpose
// [flash_attn]  512-thr block (8 waves = 2/SIMD), split-K x2, grid 256 = 1 block/CU.
//               Swapped QK^T, lane-local softmax + defer-max (T13), in-lane P repack,
//               PV; stores l-normalized O^T f16 + (m,l). setprio around MFMA (T5).
// [proj_combine] fused split-K combine + proj GEMM

#define N_TOK 4096
#define DH 128
#define NH 8

typedef _Float16 f16;
typedef __attribute__((ext_vector_type(8))) _Float16 f16x8;
typedef __attribute__((ext_vector_type(2))) __fp16 hf2;
typedef __attribute__((ext_vector_type(4))) float f32x4;

#define GLD16(gsrc, ldst) __builtin_amdgcn_global_load_lds( \
    (const __attribute__((address_space(1))) void*)(gsrc), \
    (__attribute__((address_space(3))) void*)(ldst), 16, 0, 0)

// ---------------- conv: w_proj -> f16 transposed [128 out][1024 in] ------
__global__ __launch_bounds__(256) void conv_wproj(
    const float* __restrict__ w_proj, f16* __restrict__ wpT)
{
  int t = blockIdx.x * 256 + threadIdx.x;   // 131072
  int k = t >> 7, col = t & 127;
  wpT[col * 1024 + k] = (f16)w_proj[t];
}

// ---------------- conv: w_qkv -> permuted-transposed f16 -----------------
// col' = s*1024 + h*128 + d  <->  col = h*384 + d*3 + s
__global__ __launch_bounds__(256) void conv_wqkv(
    const float* __restrict__ w_qkv, const float* __restrict__ b_qkv,
    f16* __restrict__ wqkvT, float* __restrict__ bperm)
{
  int t = blockIdx.x * 256 + threadIdx.x;   // 393216 = 3072*128
  int colp = t >> 7, k = t & 127;
  int s = colp >> 10, rem = colp & 1023, hh = rem >> 7, d = rem & 127;
  int col = hh * 384 + d * 3 + s;
  wqkvT[t] = (f16)w_qkv[k * 3072 + col];
  if (k == 0) bperm[colp] = b_qkv[col];
}

// ---------------- qkv GEMM v2: f16 MFMA --------------------------------
__global__ __launch_bounds__(256) void qkv_gemm2(
    const float* __restrict__ x, const f16* __restrict__ wqkvT,
    const float* __restrict__ bperm,
    f16* __restrict__ Qh, f16* __restrict__ Kh, f16* __restrict__ Vt)
{
  const int cb = blockIdx.x;               // 0..23: s = cb>>3, h = cb&7
  const int rb = blockIdx.y;               // 0..31: rows rb*128
  const int tid = threadIdx.x;
  const int w = tid >> 6, lane = tid & 63;
  const int l16 = lane & 15, lhi = lane >> 4;
  const int s = cb >> 3, h = cb & 7;

  f16x8 xf[2][4];
#pragma unroll
  for (int m = 0; m < 2; ++m)
#pragma unroll
    for (int kt = 0; kt < 4; ++kt) {
      const float* xp = x + (size_t)(rb * 128 + w * 32 + m * 16 + l16) * 128 + kt * 32 + lhi * 8;
      f32x4 x0 = *(const f32x4*)xp, x1 = *(const f32x4*)(xp + 4);
      f16x8 v;
#pragma unroll
      for (int j = 0; j < 4; ++j) { v[j] = (f16)x0[j]; v[4 + j] = (f16)x1[j]; }
      xf[m][kt] = v;
    }

  f32x4 acc[8][2];
#pragma unroll
  for (int nt = 0; nt < 8; ++nt)
#pragma unroll
    for (int m = 0; m < 2; ++m) acc[nt][m] = (f32x4){0.f, 0.f, 0.f, 0.f};

#pragma unroll
  for (int nt = 0; nt < 8; ++nt)
#pragma unroll
    for (int kt = 0; kt < 4; ++kt) {
      f16x8 wf = *(const f16x8*)(wqkvT + (size_t)(cb * 128 + nt * 16 + l16) * 128 + kt * 32 + lhi * 8);
      acc[nt][0] = __builtin_amdgcn_mfma_f32_16x16x32_f16(wf, xf[0][kt], acc[nt][0], 0, 0, 0);
      acc[nt][1] = __builtin_amdgcn_mfma_f32_16x16x32_f16(wf, xf[1][kt], acc[nt][1], 0, 0, 0);
    }

#pragma unroll
  for (int nt = 0; nt < 8; ++nt) {
    f32x4 bb = *(const f32x4*)(bperm + cb * 128 + nt * 16 + 4 * lhi);
#pragma unroll
    for (int m = 0; m < 2; ++m) acc[nt][m] += bb;
  }

  if (s == 2) {            // V: direct d-major store [h*128+d][n]
#pragma unroll
    for (int nt = 0; nt < 8; ++nt)
#pragma unroll
      for (int m = 0; m < 2; ++m)
#pragma unroll
        for (int r = 0; r < 4; ++r)
          Vt[(size_t)(h * 128 + nt * 16 + 4 * lhi + r) * N_TOK + rb * 128 + w * 32 + m * 16 + l16] =
              (f16)acc[nt][m][r];
  } else {                 // Q/K: LDS transpose -> n-major [n][d]
    __shared__ f16 tr[128][136];
#pragma unroll
    for (int nt = 0; nt < 8; ++nt)
#pragma unroll
      for (int m = 0; m < 2; ++m)
#pragma unroll
        for (int r = 0; r < 4; ++r)
          tr[w * 32 + m * 16 + l16][nt * 16 + 4 * lhi + r] = (f16)acc[nt][m][r];
    __syncthreads();
    f16* dst = (s == 0 ? Qh : Kh) + (size_t)(h * N_TOK + rb * 128) * 128;
    int r = tid >> 1, dh = (tid & 1) * 64;
#pragma unroll
    for (int i = 0; i < 8; ++i)
      *(f16x8*)(dst + r * 128 + dh + i * 8) = *(const f16x8*)(&tr[r][dh + i * 8]);
  }
}

// ---------------- flash attention: 8 waves, split-K x2 -------------------
// grid 256: h = bid&7 (XCD pin), sp = (bid>>3)&1, qb = bid>>4 (0..15).
// Block covers 256 q-rows (wave w -> rows qb*256 + w*32 .. +32).
__global__ __launch_bounds__(512, 2) void flash_attn(
    const f16* __restrict__ Qh, const f16* __restrict__ Kh,
    const f16* __restrict__ Vt, f16* __restrict__ opart, float* __restrict__ mlpart)
{
  const int bid = blockIdx.x;
  const int h = bid & 7, sp = (bid >> 3) & 1, qb = bid >> 4;
  const int tid = threadIdx.x;
  const int w = tid >> 6, lane = tid & 63;
  const int l16 = lane & 15, lhi = lane >> 4;

  __shared__ __align__(16) char smem[65536];   // kbuf[2] @0/16K, vbuf[2] @32K/48K

  f16x8 qf[2][4];
#pragma unroll
  for (int m = 0; m < 2; ++m)
#pragma unroll
    for (int kt = 0; kt < 4; ++kt)
      qf[m][kt] = *(const f16x8*)(Qh +
          (size_t)(h * N_TOK + qb * 256 + w * 32 + m * 16 + l16) * DH + kt * 32 + lhi * 8);

  // K A-row permutation pi = 32*(nt>>1) + 8*(i>>2) + 4*(nt&1) + (i&3); XOR swizzle
  int koff[4][4], voff[2][8];
#pragma unroll
  for (int nt = 0; nt < 4; ++nt) {
    int row = 32 * (nt >> 1) + 8 * (l16 >> 2) + 4 * (nt & 1) + (l16 & 3);
    int fk = (row & 3) | ((row & 8) >> 1);
#pragma unroll
    for (int kt = 0; kt < 4; ++kt)
      koff[nt][kt] = row * 256 + ((kt * 4 + lhi) ^ fk) * 16;
  }
#pragma unroll
  for (int ks = 0; ks < 2; ++ks)
#pragma unroll
    for (int dt = 0; dt < 8; ++dt) {
      int rowv = dt * 16 + l16;
      voff[ks][dt] = rowv * 128 + (((ks * 4 + lhi) ^ (rowv & 7))) * 16;
    }

  f32x4 o[2][8];
#pragma unroll
  for (int m = 0; m < 2; ++m)
#pragma unroll
    for (int dt = 0; dt < 8; ++dt) o[m][dt] = (f32x4){0.f, 0.f, 0.f, 0.f};
  float mrun[2] = {-3e38f, -3e38f}, lrun[2] = {0.f, 0.f};

  const f16* Kgh = Kh + (size_t)h * N_TOK * DH;
  const f16* Vgh = Vt + (size_t)h * DH * N_TOK;

  // 8 waves stage 32 KB: wave w loads K chunks {2w, 2w+1} + V chunks {2w, 2w+1}
  auto stage = [&](int buf, int kb) {
    char* kd = smem + buf * 16384;
    char* vd = smem + 32768 + buf * 16384;
#pragma unroll
    for (int c2 = 0; c2 < 2; ++c2) {
      int c = w * 2 + c2;   // 0..15
      {
        int row = c * 4 + (lane >> 4);
        int fk = (row & 3) | ((row & 8) >> 1);
        const f16* src = Kgh + (size_t)(kb * 64 + row) * DH + ((lane & 15) ^ fk) * 8;
        GLD16(src, kd + c * 1024);
      }
      {
        int row = c * 8 + (lane >> 3);
        const f16* src = Vgh + (size_t)row * N_TOK + kb * 64 + ((lane & 7) ^ (row & 7)) * 8;
        GLD16(src, vd + c * 1024);
      }
    }
  };

  const int kb0 = sp * 32;
  stage(0, kb0);
  __syncthreads();
  int buf = 0;
  for (int kb = kb0; kb < kb0 + 32; ++kb) {
    if (kb < kb0 + 31) stage(buf ^ 1, kb + 1);
    const char* kd = smem + buf * 16384;
    const char* vd = smem + 32768 + buf * 16384;

    f32x4 sv[2][4];
    __builtin_amdgcn_s_setprio(1);
#pragma unroll
    for (int nt = 0; nt < 4; ++nt) {
      f32x4 a0 = {0.f, 0.f, 0.f, 0.f}, a1 = {0.f, 0.f, 0.f, 0.f};
#pragma unroll
      for (int kt = 0; kt < 4; ++kt) {
        f16x8 kf = *(const f16x8*)(kd + koff[nt][kt]);
        a0 = __builtin_amdgcn_mfma_f32_16x16x32_f16(kf, qf[0][kt], a0, 0, 0, 0);
        a1 = __builtin_amdgcn_mfma_f32_16x16x32_f16(kf, qf[1][kt], a1, 0, 0, 0);
      }
      sv[0][nt] = a0; sv[1][nt] = a1;
    }
    __builtin_amdgcn_s_setprio(0);

    f16x8 pf[2][2];
#pragma unroll
    for (int m = 0; m < 2; ++m) {
      f32x4 mv;
#pragma unroll
      for (int r = 0; r < 4; ++r)
        mv[r] = fmaxf(fmaxf(sv[m][0][r], sv[m][1][r]), fmaxf(sv[m][2][r], sv[m][3][r]));
      float pmax = fmaxf(fmaxf(mv[0], mv[1]), fmaxf(mv[2], mv[3]));
      pmax = fmaxf(pmax, __shfl_xor(pmax, 16));
      pmax = fmaxf(pmax, __shfl_xor(pmax, 32));
      // T13 defer-max: only rescale when the max grew by > 8
      if (!__all(pmax - mrun[m] <= 8.f)) {
        float mnew = fmaxf(mrun[m], pmax);
        float sc = __expf(mrun[m] - mnew);
        lrun[m] *= sc;
#pragma unroll
        for (int dt = 0; dt < 8; ++dt) o[m][dt] *= sc;
        mrun[m] = mnew;
      }
      float mr = mrun[m];
      f32x4 ps = {0.f, 0.f, 0.f, 0.f};
#pragma unroll
      for (int nt = 0; nt < 4; ++nt)
#pragma unroll
        for (int r = 0; r < 4; ++r) {
          float p = __expf(sv[m][nt][r] - mr);
          sv[m][nt][r] = p;
          ps[r] += p;
        }
      float psum = (ps[0] + ps[1]) + (ps[2] + ps[3]);
      psum += __shfl_xor(psum, 16);
      psum += __shfl_xor(psum, 32);
      lrun[m] += psum;
#pragma unroll
      for (int ks = 0; ks < 2; ++ks) {
        union { f16x8 v; hf2 hh[4]; } u;
        u.hh[0] = __builtin_amdgcn_cvt_pkrtz(sv[m][2 * ks][0], sv[m][2 * ks][1]);
        u.hh[1] = __builtin_amdgcn_cvt_pkrtz(sv[m][2 * ks][2], sv[m][2 * ks][3]);
        u.hh[2] = __builtin_amdgcn_cvt_pkrtz(sv[m][2 * ks + 1][0], sv[m][2 * ks + 1][1]);
        u.hh[3] = __builtin_amdgcn_cvt_pkrtz(sv[m][2 * ks + 1][2], sv[m][2 * ks + 1][3]);
        pf[m][ks] = u.v;
      }
    }

    __builtin_amdgcn_s_setprio(1);
#pragma unroll
    for (int ks = 0; ks < 2; ++ks)
#pragma unroll
      for (int dt = 0; dt < 8; ++dt) {
        f16x8 vf = *(const f16x8*)(vd + voff[ks][dt]);
        o[0][dt] = __builtin_amdgcn_mfma_f32_16x16x32_f16(vf, pf[0][ks], o[0][dt], 0, 0, 0);
        o[1][dt] = __builtin_amdgcn_mfma_f32_16x16x32_f16(vf, pf[1][ks], o[1][dt], 0, 0, 0);
      }
    __builtin_amdgcn_s_setprio(0);

    __syncthreads();
    buf ^= 1;
  }

  // epilogue: l-normalized O^T f16 [128 d][256 n] (bounded ~|V|) + (m,l) stats
  f16* ob = opart + ((size_t)((sp * 8 + h) * 16 + qb)) * 32768;
  float* mlb = mlpart + ((size_t)((sp * 8 + h) * 16 + qb)) * 512;
#pragma unroll
  for (int m = 0; m < 2; ++m) {
    float rl = 1.0f / lrun[m];
#pragma unroll
    for (int dt = 0; dt < 8; ++dt)
#pragma unroll
      for (int r = 0; r < 4; ++r)
        ob[(dt * 16 + 4 * lhi + r) * 256 + w * 32 + m * 16 + l16] = (f16)(o[m][dt][r] * rl);
    if (lhi == 0) {
      mlb[w * 32 + m * 16 + l16] = mrun[m];
      mlb[256 + w * 32 + m * 16 + l16] = lrun[m];
    }
  }
}

// ---------------- proj GEMM with fused split-K combine -------------------
// 256 blocks x 16 rows. Combine O0/O1 (l-normalized) -> LDS A[16][1024], MFMA vs wpT.
__global__ __launch_bounds__(256) void proj_combine(
    const f16* __restrict__ opart, const float* __restrict__ mlpart,
    const f16* __restrict__ wpT, const float* __restrict__ b_proj,
    float* __restrict__ out)
{
  const int tid = threadIdx.x;
  const int w = tid >> 6;
  const int lane = tid & 63;
  const int l16 = lane & 15, lhi = lane >> 4;
  const int rb = blockIdx.x * 16;
  const int qb = rb >> 8;            // opart tile (256 rows)
  const int nl0 = rb & 255;          // n offset within tile

  __shared__ f16 A[16][1032];        // [n][k = h*128+d], +8 pad
  __shared__ float wl[8][16][3];     // per (h, n): c0, c1, rl
  __shared__ float red[4][16][128];

  const float isc = 0.08838834764831845f;  // 1/sqrt(128)
  if (tid < 128) {
    int hh = tid >> 4, n = tid & 15;
    const float* ml0 = mlpart + ((size_t)((0 + hh) * 16 + qb)) * 512 + nl0 + n;
    const float* ml1 = mlpart + ((size_t)((8 + hh) * 16 + qb)) * 512 + nl0 + n;
    float m0 = ml0[0], l0 = ml0[256], m1 = ml1[0], l1 = ml1[256];
    float mt = fmaxf(m0, m1);
    float n0 = __expf(m0 - mt) * l0, n1 = __expf(m1 - mt) * l1;
    wl[hh][n][0] = n0; wl[hh][n][1] = n1;
    wl[hh][n][2] = isc / (n0 + n1);
  }
  __syncthreads();

  {
    int d = tid >> 1, nn = (tid & 1) * 8;
#pragma unroll
    for (int hh = 0; hh < 8; ++hh) {
      const f16* O0 = opart + ((size_t)((0 + hh) * 16 + qb)) * 32768 + d * 256 + nl0 + nn;
      const f16* O1 = opart + ((size_t)((8 + hh) * 16 + qb)) * 32768 + d * 256 + nl0 + nn;
      f16x8 a0 = *(const f16x8*)O0, a1 = *(const f16x8*)O1;
#pragma unroll
      for (int j = 0; j < 8; ++j) {
        int n = nn + j;
        float v = ((float)a0[j] * wl[hh][n][0] + (float)a1[j] * wl[hh][n][1]) * wl[hh][n][2];
        A[n][hh * 128 + d] = (f16)v;
      }
    }
  }
  __syncthreads();

  f32x4 o[8];
#pragma unroll
  for (int dt = 0; dt < 8; ++dt) o[dt] = (f32x4){0.f, 0.f, 0.f, 0.f};

#pragma unroll
  for (int kb = 0; kb < 8; ++kb) {
    int k0 = w * 256 + kb * 32 + lhi * 8;
    f16x8 a = *(const f16x8*)(&A[l16][k0]);
#pragma unroll
    for (int dt = 0; dt < 8; ++dt) {
      f16x8 b = *(const f16x8*)(wpT + (size_t)(dt * 16 + l16) * 1024 + k0);
      o[dt] = __builtin_amdgcn_mfma_f32_16x16x32_f16(a, b, o[dt], 0, 0, 0);
    }
  }

#pragma unroll
  for (int dt = 0; dt < 8; ++dt)
#pragma unroll
    for (int r = 0; r < 4; ++r)
      red[w][lhi * 4 + r][dt * 16 + l16] = o[dt][r];
  __syncthreads();
#pragma unroll
  for (int i = 0; i < 8; ++i) {
    int idx = tid + 256 * i;
    int row = idx >> 7, col = idx & 127;
    float v = red[0][row][col] + red[1][row][col] + red[2][row][col]
            + red[3][row][col] + b_proj[col];
    out[(size_t)(rb + row) * 128 + col] = v;
  }
}

// ---------------- launch --------------------------------------------------
extern "C" void kernel_launch(void* const* d_in, const int* in_sizes, int n_in,
                              void* d_out, int out_size, void* d_ws, size_t ws_size,
                              hipStream_t stream) {
  const float* x      = (const float*)d_in[0];
  const float* w_qkv  = (const float*)d_in[1];
  const float* b_qkv  = (const float*)d_in[2];
  const float* w_proj = (const float*)d_in[3];
  const float* b_proj = (const float*)d_in[4];
  float* out = (float*)d_out;

  char* ws = (char*)d_ws;
  const size_t MB = 1024 * 1024;
  f16*   Qh     = (f16*)(ws);                    // 8 MiB  [h][n][d]
  f16*   Kh     = (f16*)(ws + 8 * MB);           // 8 MiB  [h][n][d]
  f16*   Vt     = (f16*)(ws + 16 * MB);          // 8 MiB  [h][d][n]
  f16*   opart  = (f16*)(ws + 24 * MB);          // 16 MiB [sp][h][qb][d 128][n 256]
  float* mlpart = (float*)(ws + 40 * MB);        // 0.5 MiB
  f16*   wpT    = (f16*)(ws + 40 * MB + 512 * 1024);          // 0.25 MiB
  f16*   wqkvT  = (f16*)(ws + 40 * MB + 768 * 1024);          // 0.75 MiB
  float* bperm  = (float*)(ws + 41 * MB + 512 * 1024);        // 12 KiB

  hipLaunchKernelGGL(conv_wproj, dim3(512), dim3(256), 0, stream, w_proj, wpT);
  hipLaunchKernelGGL(conv_wqkv, dim3(1536), dim3(256), 0, stream, w_qkv, b_qkv, wqkvT, bperm);
  hipLaunchKernelGGL(qkv_gemm2, dim3(24, 32), dim3(256), 0, stream,
                     x, wqkvT, bperm, Qh, Kh, Vt);
  hipLaunchKernelGGL(flash_attn, dim3(256), dim3(512), 0, stream,
                     Qh, Kh, Vt, opart, mlpart);
  hipLaunchKernelGGL(proj_combine, dim3(256), dim3(256), 0, stream,
                     opart, mlpart, wpT, b_proj, out);
}

// Round 7
// 134.293 us; speedup vs baseline: 3.7780x; 1.0448x over previous
//
#include <hip/hip_runtime.h>
#include <hip/hip_fp16.h>

// MultiHeadAttention: n=4096, e=128, H=8, fp32 in/out.
// [conv_wproj]  w_proj -> f16^T [128 out][1024 in]
// [conv_wqkv]   w_qkv -> f16 permuted-transposed wqkvT[col'][k]; Q pre-scaled by
//               log2(e) so flash softmax runs in exp2 units (bare v_exp_f32)
// [qkv_gemm2]   f16 MFMA GEMM; V stored d-major, Q/K n-major via LDS transpose
// [flash_attn]  512-thr block (8 waves = 2/SIMD), split-K x2, grid 256 = 1 block/CU.
//               Swapped QK^T, lane-local softmax, defer-max with shfl-free common
//               path, per-lane partial lrun reduced in epilogue, in-lane P repack,
//               PV. setprio around MFMA.
// [proj_combine] fused split-K combine (exp2-scale stats) + proj GEMM

#define N_TOK 4096
#define DH 128
#define NH 8

#define EXP2F(x) __builtin_amdgcn_exp2f(x)

typedef _Float16 f16;
typedef __attribute__((ext_vector_type(8))) _Float16 f16x8;
typedef __attribute__((ext_vector_type(2))) __fp16 hf2;
typedef __attribute__((ext_vector_type(4))) float f32x4;

#define GLD16(gsrc, ldst) __builtin_amdgcn_global_load_lds( \
    (const __attribute__((address_space(1))) void*)(gsrc), \
    (__attribute__((address_space(3))) void*)(ldst), 16, 0, 0)

// ---------------- conv: w_proj -> f16 transposed [128 out][1024 in] ------
__global__ __launch_bounds__(256) void conv_wproj(
    const float* __restrict__ w_proj, f16* __restrict__ wpT)
{
  int t = blockIdx.x * 256 + threadIdx.x;   // 131072
  int k = t >> 7, col = t & 127;
  wpT[col * 1024 + k] = (f16)w_proj[t];
}

// ---------------- conv: w_qkv -> permuted-transposed f16 -----------------
// k-major indexing: coalesced w_qkv reads. col' = s*1024 + h*128 + d.
// Q (s==0) scaled by log2(e) -> flash logits in log2 units.
__global__ __launch_bounds__(256) void conv_wqkv(
    const float* __restrict__ w_qkv, const float* __restrict__ b_qkv,
    f16* __restrict__ wqkvT, float* __restrict__ bperm)
{
  int t = blockIdx.x * 256 + threadIdx.x;   // 393216 = 128 * 3072
  int k = t / 3072;
  int col = t - k * 3072;
  int hh = col / 384;
  int rem = col - hh * 384;
  int d = rem / 3;
  int s = rem - d * 3;
  int colp = s * 1024 + hh * 128 + d;
  float scale = (s == 0) ? 1.4426950408889634f : 1.0f;
  wqkvT[colp * 128 + k] = (f16)(w_qkv[t] * scale);
  if (k == 0) bperm[colp] = b_qkv[col] * scale;
}

// ---------------- qkv GEMM v2: f16 MFMA --------------------------------
__global__ __launch_bounds__(256) void qkv_gemm2(
    const float* __restrict__ x, const f16* __restrict__ wqkvT,
    const float* __restrict__ bperm,
    f16* __restrict__ Qh, f16* __restrict__ Kh, f16* __restrict__ Vt)
{
  const int cb = blockIdx.x;               // 0..23: s = cb>>3, h = cb&7
  const int rb = blockIdx.y;               // 0..31: rows rb*128
  const int tid = threadIdx.x;
  const int w = tid >> 6, lane = tid & 63;
  const int l16 = lane & 15, lhi = lane >> 4;
  const int s = cb >> 3, h = cb & 7;

  f16x8 xf[2][4];
#pragma unroll
  for (int m = 0; m < 2; ++m)
#pragma unroll
    for (int kt = 0; kt < 4; ++kt) {
      const float* xp = x + (size_t)(rb * 128 + w * 32 + m * 16 + l16) * 128 + kt * 32 + lhi * 8;
      f32x4 x0 = *(const f32x4*)xp, x1 = *(const f32x4*)(xp + 4);
      f16x8 v;
#pragma unroll
      for (int j = 0; j < 4; ++j) { v[j] = (f16)x0[j]; v[4 + j] = (f16)x1[j]; }
      xf[m][kt] = v;
    }

  f32x4 acc[8][2];
#pragma unroll
  for (int nt = 0; nt < 8; ++nt)
#pragma unroll
    for (int m = 0; m < 2; ++m) acc[nt][m] = (f32x4){0.f, 0.f, 0.f, 0.f};

#pragma unroll
  for (int nt = 0; nt < 8; ++nt)
#pragma unroll
    for (int kt = 0; kt < 4; ++kt) {
      f16x8 wf = *(const f16x8*)(wqkvT + (size_t)(cb * 128 + nt * 16 + l16) * 128 + kt * 32 + lhi * 8);
      acc[nt][0] = __builtin_amdgcn_mfma_f32_16x16x32_f16(wf, xf[0][kt], acc[nt][0], 0, 0, 0);
      acc[nt][1] = __builtin_amdgcn_mfma_f32_16x16x32_f16(wf, xf[1][kt], acc[nt][1], 0, 0, 0);
    }

#pragma unroll
  for (int nt = 0; nt < 8; ++nt) {
    f32x4 bb = *(const f32x4*)(bperm + cb * 128 + nt * 16 + 4 * lhi);
#pragma unroll
    for (int m = 0; m < 2; ++m) acc[nt][m] += bb;
  }

  if (s == 2) {            // V: direct d-major store [h*128+d][n]
#pragma unroll
    for (int nt = 0; nt < 8; ++nt)
#pragma unroll
      for (int m = 0; m < 2; ++m)
#pragma unroll
        for (int r = 0; r < 4; ++r)
          Vt[(size_t)(h * 128 + nt * 16 + 4 * lhi + r) * N_TOK + rb * 128 + w * 32 + m * 16 + l16] =
              (f16)acc[nt][m][r];
  } else {                 // Q/K: LDS transpose -> n-major [n][d]
    __shared__ f16 tr[128][136];
#pragma unroll
    for (int nt = 0; nt < 8; ++nt)
#pragma unroll
      for (int m = 0; m < 2; ++m)
#pragma unroll
        for (int r = 0; r < 4; ++r)
          tr[w * 32 + m * 16 + l16][nt * 16 + 4 * lhi + r] = (f16)acc[nt][m][r];
    __syncthreads();
    f16* dst = (s == 0 ? Qh : Kh) + (size_t)(h * N_TOK + rb * 128) * 128;
    int r = tid >> 1, dh = (tid & 1) * 64;
#pragma unroll
    for (int i = 0; i < 8; ++i)
      *(f16x8*)(dst + r * 128 + dh + i * 8) = *(const f16x8*)(&tr[r][dh + i * 8]);
  }
}

// ---------------- flash attention: 8 waves, split-K x2 -------------------
// grid 256: h = bid&7 (XCD pin), sp = (bid>>3)&1, qb = bid>>4 (0..15).
__global__ __launch_bounds__(512, 2) void flash_attn(
    const f16* __restrict__ Qh, const f16* __restrict__ Kh,
    const f16* __restrict__ Vt, f16* __restrict__ opart, float* __restrict__ mlpart)
{
  const int bid = blockIdx.x;
  const int h = bid & 7, sp = (bid >> 3) & 1, qb = bid >> 4;
  const int tid = threadIdx.x;
  const int w = tid >> 6, lane = tid & 63;
  const int l16 = lane & 15, lhi = lane >> 4;

  __shared__ __align__(16) char smem[65536];   // kbuf[2] @0/16K, vbuf[2] @32K/48K

  f16x8 qf[2][4];
#pragma unroll
  for (int m = 0; m < 2; ++m)
#pragma unroll
    for (int kt = 0; kt < 4; ++kt)
      qf[m][kt] = *(const f16x8*)(Qh +
          (size_t)(h * N_TOK + qb * 256 + w * 32 + m * 16 + l16) * DH + kt * 32 + lhi * 8);

  // K A-row permutation pi = 32*(nt>>1) + 8*(i>>2) + 4*(nt&1) + (i&3); XOR swizzle
  int koff[4][4], voff[2][8];
#pragma unroll
  for (int nt = 0; nt < 4; ++nt) {
    int row = 32 * (nt >> 1) + 8 * (l16 >> 2) + 4 * (nt & 1) + (l16 & 3);
    int fk = (row & 3) | ((row & 8) >> 1);
#pragma unroll
    for (int kt = 0; kt < 4; ++kt)
      koff[nt][kt] = row * 256 + ((kt * 4 + lhi) ^ fk) * 16;
  }
#pragma unroll
  for (int ks = 0; ks < 2; ++ks)
#pragma unroll
    for (int dt = 0; dt < 8; ++dt) {
      int rowv = dt * 16 + l16;
      voff[ks][dt] = rowv * 128 + (((ks * 4 + lhi) ^ (rowv & 7))) * 16;
    }

  f32x4 o[2][8];
#pragma unroll
  for (int m = 0; m < 2; ++m)
#pragma unroll
    for (int dt = 0; dt < 8; ++dt) o[m][dt] = (f32x4){0.f, 0.f, 0.f, 0.f};
  float mrun[2] = {-3e38f, -3e38f}, lrun[2] = {0.f, 0.f};   // lrun: per-lane partial

  const f16* Kgh = Kh + (size_t)h * N_TOK * DH;
  const f16* Vgh = Vt + (size_t)h * DH * N_TOK;

  auto stage = [&](int buf, int kb) {
    char* kd = smem + buf * 16384;
    char* vd = smem + 32768 + buf * 16384;
#pragma unroll
    for (int c2 = 0; c2 < 2; ++c2) {
      int c = w * 2 + c2;   // 0..15
      {
        int row = c * 4 + (lane >> 4);
        int fk = (row & 3) | ((row & 8) >> 1);
        const f16* src = Kgh + (size_t)(kb * 64 + row) * DH + ((lane & 15) ^ fk) * 8;
        GLD16(src, kd + c * 1024);
      }
      {
        int row = c * 8 + (lane >> 3);
        const f16* src = Vgh + (size_t)row * N_TOK + kb * 64 + ((lane & 7) ^ (row & 7)) * 8;
        GLD16(src, vd + c * 1024);
      }
    }
  };

  const int kb0 = sp * 32;
  stage(0, kb0);
  __syncthreads();
  int buf = 0;
  for (int kb = kb0; kb < kb0 + 32; ++kb) {
    if (kb < kb0 + 31) stage(buf ^ 1, kb + 1);
    const char* kd = smem + buf * 16384;
    const char* vd = smem + 32768 + buf * 16384;

    f32x4 sv[2][4];
    __builtin_amdgcn_s_setprio(1);
#pragma unroll
    for (int nt = 0; nt < 4; ++nt) {
      f32x4 a0 = {0.f, 0.f, 0.f, 0.f}, a1 = {0.f, 0.f, 0.f, 0.f};
#pragma unroll
      for (int kt = 0; kt < 4; ++kt) {
        f16x8 kf = *(const f16x8*)(kd + koff[nt][kt]);
        a0 = __builtin_amdgcn_mfma_f32_16x16x32_f16(kf, qf[0][kt], a0, 0, 0, 0);
        a1 = __builtin_amdgcn_mfma_f32_16x16x32_f16(kf, qf[1][kt], a1, 0, 0, 0);
      }
      sv[0][nt] = a0; sv[1][nt] = a1;
    }
    __builtin_amdgcn_s_setprio(0);

    f16x8 pf[2][2];
#pragma unroll
    for (int m = 0; m < 2; ++m) {
      f32x4 mv;
#pragma unroll
      for (int r = 0; r < 4; ++r)
        mv[r] = fmaxf(fmaxf(sv[m][0][r], sv[m][1][r]), fmaxf(sv[m][2][r], sv[m][3][r]));
      float pmax = fmaxf(fmaxf(mv[0], mv[1]), fmaxf(mv[2], mv[3]));
      // defer-max, shfl-free common path: lane-local threshold check (log2 units)
      if (!__all(pmax - mrun[m] <= 8.f)) {
        float rm = fmaxf(pmax, __shfl_xor(pmax, 16));
        rm = fmaxf(rm, __shfl_xor(rm, 32));
        float mnew = fmaxf(mrun[m], rm);
        float sc = EXP2F(mrun[m] - mnew);
        lrun[m] *= sc;
#pragma unroll
        for (int dt = 0; dt < 8; ++dt) o[m][dt] *= sc;
        mrun[m] = mnew;
      }
      float mr = mrun[m];
      f32x4 ps = {0.f, 0.f, 0.f, 0.f};
#pragma unroll
      for (int nt = 0; nt < 4; ++nt)
#pragma unroll
        for (int r = 0; r < 4; ++r) {
          float p = EXP2F(sv[m][nt][r] - mr);
          sv[m][nt][r] = p;
          ps[r] += p;
        }
      lrun[m] += (ps[0] + ps[1]) + (ps[2] + ps[3]);   // per-lane partial sum
#pragma unroll
      for (int ks = 0; ks < 2; ++ks) {
        union { f16x8 v; hf2 hh[4]; } u;
        u.hh[0] = __builtin_amdgcn_cvt_pkrtz(sv[m][2 * ks][0], sv[m][2 * ks][1]);
        u.hh[1] = __builtin_amdgcn_cvt_pkrtz(sv[m][2 * ks][2], sv[m][2 * ks][3]);
        u.hh[2] = __builtin_amdgcn_cvt_pkrtz(sv[m][2 * ks + 1][0], sv[m][2 * ks + 1][1]);
        u.hh[3] = __builtin_amdgcn_cvt_pkrtz(sv[m][2 * ks + 1][2], sv[m][2 * ks + 1][3]);
        pf[m][ks] = u.v;
      }
    }

    __builtin_amdgcn_s_setprio(1);
#pragma unroll
    for (int ks = 0; ks < 2; ++ks)
#pragma unroll
      for (int dt = 0; dt < 8; ++dt) {
        f16x8 vf = *(const f16x8*)(vd + voff[ks][dt]);
        o[0][dt] = __builtin_amdgcn_mfma_f32_16x16x32_f16(vf, pf[0][ks], o[0][dt], 0, 0, 0);
        o[1][dt] = __builtin_amdgcn_mfma_f32_16x16x32_f16(vf, pf[1][ks], o[1][dt], 0, 0, 0);
      }
    __builtin_amdgcn_s_setprio(0);

    __syncthreads();
    buf ^= 1;
  }

  // epilogue: reduce lrun across lanes, store l-normalized O^T f16 + (m,l)
  f16* ob = opart + ((size_t)((sp * 8 + h) * 16 + qb)) * 32768;
  float* mlb = mlpart + ((size_t)((sp * 8 + h) * 16 + qb)) * 512;
#pragma unroll
  for (int m = 0; m < 2; ++m) {
    float lr = lrun[m];
    lr += __shfl_xor(lr, 16);
    lr += __shfl_xor(lr, 32);
    float rl = 1.0f / lr;
#pragma unroll
    for (int dt = 0; dt < 8; ++dt)
#pragma unroll
      for (int r = 0; r < 4; ++r)
        ob[(dt * 16 + 4 * lhi + r) * 256 + w * 32 + m * 16 + l16] = (f16)(o[m][dt][r] * rl);
    if (lhi == 0) {
      mlb[w * 32 + m * 16 + l16] = mrun[m];
      mlb[256 + w * 32 + m * 16 + l16] = lr;
    }
  }
}

// ---------------- proj GEMM with fused split-K combine -------------------
__global__ __launch_bounds__(256) void proj_combine(
    const f16* __restrict__ opart, const float* __restrict__ mlpart,
    const f16* __restrict__ wpT, const float* __restrict__ b_proj,
    float* __restrict__ out)
{
  const int tid = threadIdx.x;
  const int w = tid >> 6;
  const int lane = tid & 63;
  const int l16 = lane & 15, lhi = lane >> 4;
  const int rb = blockIdx.x * 16;
  const int qb = rb >> 8;            // opart tile (256 rows)
  const int nl0 = rb & 255;          // n offset within tile

  __shared__ f16 A[16][1032];        // [n][k = h*128+d], +8 pad
  __shared__ float wl[8][16][3];     // per (h, n): c0, c1, rl
  __shared__ float red[4][16][128];

  const float isc = 0.08838834764831845f;  // 1/sqrt(128)
  if (tid < 128) {
    int hh = tid >> 4, n = tid & 15;
    const float* ml0 = mlpart + ((size_t)((0 + hh) * 16 + qb)) * 512 + nl0 + n;
    const float* ml1 = mlpart + ((size_t)((8 + hh) * 16 + qb)) * 512 + nl0 + n;
    float m0 = ml0[0], l0 = ml0[256], m1 = ml1[0], l1 = ml1[256];
    float mt = fmaxf(m0, m1);
    float n0 = EXP2F(m0 - mt) * l0, n1 = EXP2F(m1 - mt) * l1;  // log2-scale stats
    wl[hh][n][0] = n0; wl[hh][n][1] = n1;
    wl[hh][n][2] = isc / (n0 + n1);
  }
  __syncthreads();

  {
    int d = tid >> 1, nn = (tid & 1) * 8;
#pragma unroll
    for (int hh = 0; hh < 8; ++hh) {
      const f16* O0 = opart + ((size_t)((0 + hh) * 16 + qb)) * 32768 + d * 256 + nl0 + nn;
      const f16* O1 = opart + ((size_t)((8 + hh) * 16 + qb)) * 32768 + d * 256 + nl0 + nn;
      f16x8 a0 = *(const f16x8*)O0, a1 = *(const f16x8*)O1;
#pragma unroll
      for (int j = 0; j < 8; ++j) {
        int n = nn + j;
        float v = ((float)a0[j] * wl[hh][n][0] + (float)a1[j] * wl[hh][n][1]) * wl[hh][n][2];
        A[n][hh * 128 + d] = (f16)v;
      }
    }
  }
  __syncthreads();

  f32x4 o[8];
#pragma unroll
  for (int dt = 0; dt < 8; ++dt) o[dt] = (f32x4){0.f, 0.f, 0.f, 0.f};

#pragma unroll
  for (int kb = 0; kb < 8; ++kb) {
    int k0 = w * 256 + kb * 32 + lhi * 8;
    f16x8 a = *(const f16x8*)(&A[l16][k0]);
#pragma unroll
    for (int dt = 0; dt < 8; ++dt) {
      f16x8 b = *(const f16x8*)(wpT + (size_t)(dt * 16 + l16) * 1024 + k0);
      o[dt] = __builtin_amdgcn_mfma_f32_16x16x32_f16(a, b, o[dt], 0, 0, 0);
    }
  }

#pragma unroll
  for (int dt = 0; dt < 8; ++dt)
#pragma unroll
    for (int r = 0; r < 4; ++r)
      red[w][lhi * 4 + r][dt * 16 + l16] = o[dt][r];
  __syncthreads();
#pragma unroll
  for (int i = 0; i < 8; ++i) {
    int idx = tid + 256 * i;
    int row = idx >> 7, col = idx & 127;
    float v = red[0][row][col] + red[1][row][col] + red[2][row][col]
            + red[3][row][col] + b_proj[col];
    out[(size_t)(rb + row) * 128 + col] = v;
  }
}

// ---------------- launch --------------------------------------------------
extern "C" void kernel_launch(void* const* d_in, const int* in_sizes, int n_in,
                              void* d_out, int out_size, void* d_ws, size_t ws_size,
                              hipStream_t stream) {
  const float* x      = (const float*)d_in[0];
  const float* w_qkv  = (const float*)d_in[1];
  const float* b_qkv  = (const float*)d_in[2];
  const float* w_proj = (const float*)d_in[3];
  const float* b_proj = (const float*)d_in[4];
  float* out = (float*)d_out;

  char* ws = (char*)d_ws;
  const size_t MB = 1024 * 1024;
  f16*   Qh     = (f16*)(ws);                    // 8 MiB  [h][n][d]
  f16*   Kh     = (f16*)(ws + 8 * MB);           // 8 MiB  [h][n][d]
  f16*   Vt     = (f16*)(ws + 16 * MB);          // 8 MiB  [h][d][n]
  f16*   opart  = (f16*)(ws + 24 * MB);          // 16 MiB [sp][h][qb][d 128][n 256]
  float* mlpart = (float*)(ws + 40 * MB);        // 0.5 MiB
  f16*   wpT    = (f16*)(ws + 40 * MB + 512 * 1024);          // 0.25 MiB
  f16*   wqkvT  = (f16*)(ws + 40 * MB + 768 * 1024);          // 0.75 MiB
  float* bperm  = (float*)(ws + 41 * MB + 512 * 1024);        // 12 KiB

  hipLaunchKernelGGL(conv_wproj, dim3(512), dim3(256), 0, stream, w_proj, wpT);
  hipLaunchKernelGGL(conv_wqkv, dim3(1536), dim3(256), 0, stream, w_qkv, b_qkv, wqkvT, bperm);
  hipLaunchKernelGGL(qkv_gemm2, dim3(24, 32), dim3(256), 0, stream,
                     x, wqkvT, bperm, Qh, Kh, Vt);
  hipLaunchKernelGGL(flash_attn, dim3(256), dim3(512), 0, stream,
                     Qh, Kh, Vt, opart, mlpart);
  hipLaunchKernelGGL(proj_combine, dim3(256), dim3(256), 0, stream,
                     opart, mlpart, wpT, b_proj, out);
}